// Round 2
// baseline (395.540 us; speedup 1.0000x reference)
//
#include <hip/hip_runtime.h>

typedef __bf16 bf16_t;
typedef __bf16 bf16x8 __attribute__((ext_vector_type(8)));
typedef float f32x4 __attribute__((ext_vector_type(4)));

#define CTOT 320
#define NPIX 32768  // 8*64*64

// ---------- P1: y [b][c][h][w] f32 -> yt [pix][320] bf16 (pixel-major) ----------
__global__ __launch_bounds__(256) void k_transpose_y(const float* __restrict__ y,
                                                     bf16_t* __restrict__ yt) {
  __shared__ bf16_t T[64][72];
  int blk = blockIdx.x;            // (8*64) * 5 blocks
  int c0 = (blk % 5) * 64;
  int bh = blk / 5;                // b*64 + h
  int b = bh >> 6, h = bh & 63;
  int tid = threadIdx.x;
  {
    int c = tid >> 2, w0 = (tid & 3) << 4;
    const float* src = y + (size_t)(b * CTOT + c0 + c) * 4096 + (h << 6) + w0;
#pragma unroll
    for (int j = 0; j < 16; j += 4) {
      float4 v = *(const float4*)(src + j);
      T[c][w0 + j + 0] = (bf16_t)v.x;
      T[c][w0 + j + 1] = (bf16_t)v.y;
      T[c][w0 + j + 2] = (bf16_t)v.z;
      T[c][w0 + j + 3] = (bf16_t)v.w;
    }
  }
  __syncthreads();
  {
    int w = tid >> 2, cq = (tid & 3) << 4;
    union { uint4 v; bf16_t b[8]; } u0, u1;
#pragma unroll
    for (int j = 0; j < 8; ++j) { u0.b[j] = T[cq + j][w]; u1.b[j] = T[cq + 8 + j][w]; }
    bf16_t* dst = yt + (size_t)((bh << 6) | w) * CTOT + c0 + cq;
    *(uint4*)dst = u0.v;
    *(uint4*)(dst + 8) = u1.v;
  }
}

// ---------- P2: w [oc][ic][5][5] f32 -> wt [tap][OCp][ICp] bf16 (zero-padded) ----------
__global__ __launch_bounds__(256) void k_transpose_w(const float* __restrict__ w,
                                                     bf16_t* __restrict__ wt,
                                                     int IC, int ICp, int OC, int OCp) {
  int idx = blockIdx.x * 256 + threadIdx.x;
  if (idx >= OCp * ICp) return;
  int oc = idx / ICp, ic = idx - oc * ICp;
  bool valid = (oc < OC) && (ic < IC);
  const float* src = w + (size_t)(oc * IC + ic) * 25;
#pragma unroll
  for (int t = 0; t < 25; ++t) {
    float v = valid ? src[t] : 0.0f;
    wt[(size_t)(t * OCp + oc) * ICp + ic] = (bf16_t)v;
  }
}

// ---------- main: implicit-GEMM conv, tap-major K, MFMA 16x16x32 bf16 ----------
// Per-tap barriers removed: weights (A-frags) read straight from global (L2-hot),
// Sin is read-only during the tap phase. Masked convs use only the 12 odd taps.
struct ConvDesc {
  const float* bias;
  unsigned out_off;   // elements into d_out
  unsigned wt_off;    // elements into wt region
  int IC, ICp, OC, chs, masked, job_start, nmb;
};
struct MainParams {
  const bf16_t* yt;
  const bf16_t* wt;
  float* out;
  ConvDesc cv[9];
};

__global__ __launch_bounds__(256, 2) void k_conv_main(MainParams P) {
  // Sin: [icg 0..3][pixel 0..815 (12 rows x 68 cols)][8 ic], elem-XOR-swizzled
  // by (icg<<4) to kill the 4-way bank alias on staging writes (13056B % 128 == 0).
  __shared__ bf16_t Sin[4][816][8];   // 52224 B

  int bid = blockIdx.x;
  int ci = 0;
#pragma unroll
  for (int i = 1; i < 9; ++i) if (bid >= P.cv[i].job_start) ci = i;
  ConvDesc cd = P.cv[ci];
  int local = bid - cd.job_start;
  int mb = local >> 6, nb = local & 63;      // 64 n-blocks (512 px each) per m-block
  int b = nb >> 3, r0 = (nb & 7) << 3;       // 8 output rows per n-block
  int tid = threadIdx.x, lane = tid & 63, wn = tid >> 6;
  int OCp = cd.nmb << 6;

  const bf16_t* sin0 = &Sin[0][0][0];
  int qsw = (lane >> 4) << 4;                // element XOR for B-frag reads

  // per-nf fragment base offsets into Sin (elements); tap adds (dy*68+dx)*8
  int bbase[8];
#pragma unroll
  for (int nf = 0; nf < 8; ++nf) {
    int rl = (wn << 1) + (nf >> 2);                 // local output row 0..7
    int col = ((nf & 3) << 4) + (lane & 15);        // local col 0..63
    bbase[nf] = ((lane >> 4) * 6528) + (rl * 68 + col) * 8;
  }

  int mfmax = (cd.OC - (mb << 6)) >> 4; if (mfmax > 4) mfmax = 4;

  f32x4 acc[4][8];
#pragma unroll
  for (int i = 0; i < 4; ++i)
#pragma unroll
    for (int j = 0; j < 8; ++j) acc[i][j] = (f32x4){0.f, 0.f, 0.f, 0.f};

  const bf16_t* wtc = P.wt + cd.wt_off;
  // Per-lane global A base: oc = mb*64 + (lane&15) (+16*mf), k-slice (lane>>4)*8
  const bf16_t* abase_g = wtc + (size_t)((mb << 6) + (lane & 15)) * cd.ICp + ((lane >> 4) << 3);
  int tapstride = OCp * cd.ICp;   // elements per tap
  int mstride = cd.ICp << 4;      // 16 oc

  int nchunks = cd.ICp >> 5;
  for (int cb = 0; cb < nchunks; ++cb) {
    int ic0 = cb << 5;
    if (cb) __syncthreads();   // protect Sin overwrite
    // ---- stage input chunk: 12 rows x 68 cols x 32 ic, halo zero-filled ----
    // (no input parity mask needed: odd taps only touch even-parity pixels for
    //  kept outputs; garbage at non-kept outputs is zeroed in the epilogue)
    for (int task = tid; task < 3264; task += 256) {
      int pidx = task >> 2, icg = task & 3;
      int rr = pidx / 68, cc = pidx - rr * 68;
      int h = r0 + rr - 2, w = cc - 2;
      int icc = ic0 + (icg << 3);
      uint4 v = {0u, 0u, 0u, 0u};
      if (((unsigned)h < 64u) && ((unsigned)w < 64u) && (icc < cd.IC))
        v = *(const uint4*)(P.yt + (size_t)((((b << 6) + h) << 6) | w) * CTOT + cd.chs + icc);
      int eoff = (icg * 6528 + pidx * 8) ^ (icg << 4);
      *(uint4*)(sin0 + eoff) = v;
    }
    __syncthreads();

    const bf16_t* ag = abase_g + ic0;

#define TAP_BODY(T)                                                            \
    {                                                                          \
      int t_ = (T);                                                            \
      int dy_ = t_ / 5, dx_ = t_ - dy_ * 5;                                    \
      int toff_ = (dy_ * 68 + dx_) << 3;                                       \
      const bf16_t* ap_ = ag + (size_t)t_ * tapstride;                         \
      bf16x8 af[4];                                                            \
      _Pragma("unroll")                                                        \
      for (int mf = 0; mf < 4; ++mf)                                           \
        if (mf < mfmax) af[mf] = *(const bf16x8*)(ap_ + mf * mstride);         \
      _Pragma("unroll")                                                        \
      for (int nf = 0; nf < 8; ++nf) {                                         \
        bf16x8 bfrag = *(const bf16x8*)(sin0 + ((bbase[nf] + toff_) ^ qsw));   \
        _Pragma("unroll")                                                      \
        for (int mf = 0; mf < 4; ++mf)                                         \
          if (mf < mfmax)                                                      \
            acc[mf][nf] = __builtin_amdgcn_mfma_f32_16x16x32_bf16(             \
                af[mf], bfrag, acc[mf][nf], 0, 0, 0);                          \
      }                                                                        \
    }

    if (cd.masked) {
      for (int it = 0; it < 12; ++it) TAP_BODY(2 * it + 1)   // odd taps only
    } else {
      for (int it = 0; it < 25; ++it) TAP_BODY(it)
    }
#undef TAP_BODY
  }

  // ---- epilogue: bias, output mask (1-m0), store f32 ----
  float* outp = P.out + cd.out_off;
  int laneq = lane >> 4;
#pragma unroll
  for (int mf = 0; mf < 4; ++mf) {
    if (mf >= mfmax) break;
    int oc0 = (mb << 6) + (mf << 4) + (laneq << 2);
    float b0 = cd.bias[oc0], b1 = cd.bias[oc0 + 1], b2 = cd.bias[oc0 + 2], b3 = cd.bias[oc0 + 3];
    size_t obase = (size_t)(b * cd.OC + oc0) << 12;
#pragma unroll
    for (int nf = 0; nf < 8; ++nf) {
      int nl = (wn << 7) + (nf << 4) + (lane & 15);
      int rem = (r0 << 6) + nl;
      int h = rem >> 6, w = rem & 63;
      float keep = 1.0f;
      if (cd.masked && !((h + w) & 1)) keep = 0.0f;  // * (1 - m0): keep odd parity
      f32x4 a = acc[mf][nf];
      outp[obase + rem]           = (a[0] + b0) * keep;
      outp[obase + 4096 + rem]    = (a[1] + b1) * keep;
      outp[obase + 8192 + rem]    = (a[2] + b2) * keep;
      outp[obase + 12288 + rem]   = (a[3] + b3) * keep;
    }
  }
}

extern "C" void kernel_launch(void* const* d_in, const int* in_sizes, int n_in,
                              void* d_out, int out_size, void* d_ws, size_t ws_size,
                              hipStream_t stream) {
  const float* y = (const float*)d_in[0];
  bf16_t* yt = (bf16_t*)d_ws;
  bf16_t* wt = (bf16_t*)((char*)d_ws + (size_t)NPIX * CTOT * 2);  // +20,971,520 B

  k_transpose_y<<<2560, 256, 0, stream>>>(y, yt);

  // Launch order: heaviest blocks first (per-block tap-iters: ch4=100, sp4=72,
  // ch3=50, ch2/ch1=25, sp3=24, sp2/sp1/sp0=12) to avoid a heavy tail.
  //                        ch4      sp4     ch3     ch2     ch1     sp3     sp2     sp1    sp0
  static const int IC[9]   = {128,    192,    64,     32,     16,     64,     32,     16,    16};
  static const int ICp[9]  = {128,    192,    64,     32,     32,     64,     32,     32,    32};
  static const int OC[9]   = {384,    384,    128,    64,     32,     128,    64,     32,    32};
  static const int OCpA[9] = {384,    384,    128,    64,     64,     128,    64,     64,    64};
  static const int WIDX[9] = {19,     11,     17,     15,     13,     9,      7,      5,     3};
  static const int BIDX[9] = {20,     12,     18,     16,     14,     10,     8,      6,     4};
  static const int CHS[9]  = {0,      128,    0,      0,      0,      64,     32,     16,    0};
  static const int MASKED[9]={0,      1,      0,      0,      0,      1,      1,      1,     1};
  static const unsigned WTOFF[9]  = {2508800, 358400, 2304000, 2252800, 2201600,
                                     153600,  102400, 51200,   0};
  static const unsigned OUTOFF[9] = {28311552, 15728640, 11534336, 5242880, 2097152,
                                     7340032,  3145728,  1048576,  0};
  static const int JOBST[9]  = {0, 384, 768, 896, 960, 1024, 1152, 1216, 1280};

  for (int i = 0; i < 9; ++i) {
    int n = OCpA[i] * ICp[i];
    k_transpose_w<<<(n + 255) / 256, 256, 0, stream>>>(
        (const float*)d_in[WIDX[i]], wt + WTOFF[i], IC[i], ICp[i], OC[i], OCpA[i]);
  }

  MainParams P;
  P.yt = yt; P.wt = wt; P.out = (float*)d_out;
  for (int i = 0; i < 9; ++i) {
    P.cv[i].bias = (const float*)d_in[BIDX[i]];
    P.cv[i].out_off = OUTOFF[i];
    P.cv[i].wt_off = WTOFF[i];
    P.cv[i].IC = IC[i]; P.cv[i].ICp = ICp[i]; P.cv[i].OC = OC[i];
    P.cv[i].chs = CHS[i]; P.cv[i].masked = MASKED[i];
    P.cv[i].job_start = JOBST[i]; P.cv[i].nmb = OCpA[i] >> 6;
  }
  k_conv_main<<<1344, 256, 0, stream>>>(P);
}

// Round 3
// 329.909 us; speedup vs baseline: 1.1989x; 1.1989x over previous
//
#include <hip/hip_runtime.h>

typedef __bf16 bf16_t;
typedef __bf16 bf16x8 __attribute__((ext_vector_type(8)));
typedef float f32x4 __attribute__((ext_vector_type(4)));

#define CTOT 320
#define NPIX 32768  // 8*64*64

// ---------- P1: y [b][c][h][w] f32 -> yt [pix][320] bf16 (pixel-major) ----------
__global__ __launch_bounds__(256) void k_transpose_y(const float* __restrict__ y,
                                                     bf16_t* __restrict__ yt) {
  __shared__ bf16_t T[64][72];
  int blk = blockIdx.x;            // (8*64) * 5 blocks
  int c0 = (blk % 5) * 64;
  int bh = blk / 5;                // b*64 + h
  int b = bh >> 6, h = bh & 63;
  int tid = threadIdx.x;
  {
    int c = tid >> 2, w0 = (tid & 3) << 4;
    const float* src = y + (size_t)(b * CTOT + c0 + c) * 4096 + (h << 6) + w0;
#pragma unroll
    for (int j = 0; j < 16; j += 4) {
      float4 v = *(const float4*)(src + j);
      T[c][w0 + j + 0] = (bf16_t)v.x;
      T[c][w0 + j + 1] = (bf16_t)v.y;
      T[c][w0 + j + 2] = (bf16_t)v.z;
      T[c][w0 + j + 3] = (bf16_t)v.w;
    }
  }
  __syncthreads();
  {
    int w = tid >> 2, cq = (tid & 3) << 4;
    union { uint4 v; bf16_t b[8]; } u0, u1;
#pragma unroll
    for (int j = 0; j < 8; ++j) { u0.b[j] = T[cq + j][w]; u1.b[j] = T[cq + 8 + j][w]; }
    bf16_t* dst = yt + (size_t)((bh << 6) | w) * CTOT + c0 + cq;
    *(uint4*)dst = u0.v;
    *(uint4*)(dst + 8) = u1.v;
  }
}

// ---------- P2: w [oc][ic][5][5] f32 -> wt [tap][OCp][ICp] bf16 (zero-padded) ----------
__global__ __launch_bounds__(256) void k_transpose_w(const float* __restrict__ w,
                                                     bf16_t* __restrict__ wt,
                                                     int IC, int ICp, int OC, int OCp) {
  int idx = blockIdx.x * 256 + threadIdx.x;
  if (idx >= OCp * ICp) return;
  int oc = idx / ICp, ic = idx - oc * ICp;
  bool valid = (oc < OC) && (ic < IC);
  const float* src = w + (size_t)(oc * IC + ic) * 25;
#pragma unroll
  for (int t = 0; t < 25; ++t) {
    float v = valid ? src[t] : 0.0f;
    wt[(size_t)(t * OCp + oc) * ICp + ic] = (bf16_t)v;
  }
}

// ---------- main: implicit-GEMM conv, tap-major K, MFMA 16x16x32 bf16 ----------
// Weights staged in LDS, double-buffered in GROUPS OF 3 TAPS (one barrier per
// 96 MFMAs instead of per 32). Masked convs use only the 12 odd taps.
struct ConvDesc {
  const float* bias;
  unsigned out_off;   // elements into d_out
  unsigned wt_off;    // elements into wt region
  int IC, ICp, OC, chs, masked, job_start, nmb;
};
struct MainParams {
  const bf16_t* yt;
  const bf16_t* wt;
  float* out;
  ConvDesc cv[9];
};

__global__ __launch_bounds__(256, 2) void k_conv_main(MainParams P) {
  // Sin: [icg][pixel (12r x 68c)][8 ic], elem-XOR-swizzled by (icg<<4)  = 52224 B
  // Sw : [buf][tl 0..2][icg][oc][8 ic]                                  = 24576 B
  __shared__ bf16_t Sin[4][816][8];
  __shared__ bf16_t Sw[2][3][4][64][8];

  int bid = blockIdx.x;
  int ci = 0;
#pragma unroll
  for (int i = 1; i < 9; ++i) if (bid >= P.cv[i].job_start) ci = i;
  ConvDesc cd = P.cv[ci];
  int local = bid - cd.job_start;
  int mb = local >> 6, nb = local & 63;      // 64 n-blocks (512 px each) per m-block
  int b = nb >> 3, r0 = (nb & 7) << 3;       // 8 output rows per n-block
  int tid = threadIdx.x, lane = tid & 63, wn = tid >> 6;
  int OCp = cd.nmb << 6;

  const bf16_t* sin0 = &Sin[0][0][0];
  const bf16_t* sw0 = &Sw[0][0][0][0][0];
  int qsw = (lane >> 4) << 4;                // element XOR for B-frag reads

  // per-nf fragment base offsets into Sin (elements); tap adds (dy*68+dx)*8
  int bbase[8];
#pragma unroll
  for (int nf = 0; nf < 8; ++nf) {
    int rl = (wn << 1) + (nf >> 2);                 // local output row 0..7
    int col = ((nf & 3) << 4) + (lane & 15);        // local col 0..63
    bbase[nf] = ((lane >> 4) * 6528) + (rl * 68 + col) * 8;
  }
  int abase = ((lane >> 4) << 9) + ((lane & 15) << 3);

  int mfmax = (cd.OC - (mb << 6)) >> 4; if (mfmax > 4) mfmax = 4;

  f32x4 acc[4][8];
#pragma unroll
  for (int i = 0; i < 4; ++i)
#pragma unroll
    for (int j = 0; j < 8; ++j) acc[i][j] = (f32x4){0.f, 0.f, 0.f, 0.f};

  const bf16_t* wtc = P.wt + cd.wt_off;
  int s_oc = tid >> 2, s_icg = tid & 3;
  int ntaps = cd.masked ? 12 : 25;
  int ngroups = (ntaps + 2) / 3;

  int nchunks = cd.ICp >> 5;
  for (int cb = 0; cb < nchunks; ++cb) {
    int ic0 = cb << 5;
    // ---- stage input chunk: 12 rows x 68 cols x 32 ic, halo zero-filled ----
    // (prev chunk's final barrier protects Sin/Sw reuse)
    for (int task = tid; task < 3264; task += 256) {
      int pidx = task >> 2, icg = task & 3;
      int rr = pidx / 68, cc = pidx - rr * 68;
      int h = r0 + rr - 2, w = cc - 2;
      int icc = ic0 + (icg << 3);
      uint4 v = {0u, 0u, 0u, 0u};
      if (((unsigned)h < 64u) && ((unsigned)w < 64u) && (icc < cd.IC))
        v = *(const uint4*)(P.yt + (size_t)((((b << 6) + h) << 6) | w) * CTOT + cd.chs + icc);
      int eoff = (icg * 6528 + pidx * 8) ^ (icg << 4);
      *(uint4*)(sin0 + eoff) = v;
    }
    // ---- stage weight group 0 -> buf 0 ----
#pragma unroll
    for (int tl = 0; tl < 3; ++tl) {
      if (tl < ntaps) {
        int tap = cd.masked ? (2 * tl + 1) : tl;
        size_t wo = (size_t)(tap * OCp + (mb << 6) + s_oc) * cd.ICp + ic0 + (s_icg << 3);
        *(uint4*)(&Sw[0][tl][s_icg][s_oc][0]) = *(const uint4*)(wtc + wo);
      }
    }
    __syncthreads();

    for (int g = 0; g < ngroups; ++g) {
      int cur = g & 1;
      int tcnt = ntaps - 3 * g; if (tcnt > 3) tcnt = 3;
      // prefetch next group's weights into regs
      uint4 wv[3];
      int gn = g + 1;
      int pcnt = 0;
      if (gn < ngroups) {
        pcnt = ntaps - 3 * gn; if (pcnt > 3) pcnt = 3;
#pragma unroll
        for (int tl = 0; tl < 3; ++tl) {
          if (tl < pcnt) {
            int tap = cd.masked ? (6 * gn + 2 * tl + 1) : (3 * gn + tl);
            size_t wo = (size_t)(tap * OCp + (mb << 6) + s_oc) * cd.ICp + ic0 + (s_icg << 3);
            wv[tl] = *(const uint4*)(wtc + wo);
          }
        }
      }
      // MFMA over the group's taps
#pragma unroll
      for (int tl = 0; tl < 3; ++tl) {
        if (tl < tcnt) {
          int tap = cd.masked ? (6 * g + 2 * tl + 1) : (3 * g + tl);
          int dy = tap / 5, dx = tap - dy * 5;
          int toff = (dy * 68 + dx) << 3;
          const bf16_t* swc = sw0 + (cur * 3 + tl) * 2048 + abase;
          bf16x8 af[4];
#pragma unroll
          for (int mf = 0; mf < 4; ++mf)
            if (mf < mfmax) af[mf] = *(const bf16x8*)(swc + (mf << 7));
#pragma unroll
          for (int nf = 0; nf < 8; ++nf) {
            bf16x8 bfrag = *(const bf16x8*)(sin0 + ((bbase[nf] + toff) ^ qsw));
#pragma unroll
            for (int mf = 0; mf < 4; ++mf)
              if (mf < mfmax)
                acc[mf][nf] = __builtin_amdgcn_mfma_f32_16x16x32_bf16(
                    af[mf], bfrag, acc[mf][nf], 0, 0, 0);
          }
        }
      }
      // commit prefetched weights to the other buffer
      if (gn < ngroups) {
#pragma unroll
        for (int tl = 0; tl < 3; ++tl)
          if (tl < pcnt) *(uint4*)(&Sw[cur ^ 1][tl][s_icg][s_oc][0]) = wv[tl];
      }
      __syncthreads();
    }
  }

  // ---- epilogue: bias, output mask (1-m0), store f32 ----
  float* outp = P.out + cd.out_off;
  int laneq = lane >> 4;
#pragma unroll
  for (int mf = 0; mf < 4; ++mf) {
    if (mf >= mfmax) break;
    int oc0 = (mb << 6) + (mf << 4) + (laneq << 2);
    float b0 = cd.bias[oc0], b1 = cd.bias[oc0 + 1], b2 = cd.bias[oc0 + 2], b3 = cd.bias[oc0 + 3];
    size_t obase = (size_t)(b * cd.OC + oc0) << 12;
#pragma unroll
    for (int nf = 0; nf < 8; ++nf) {
      int nl = (wn << 7) + (nf << 4) + (lane & 15);
      int rem = (r0 << 6) + nl;
      int h = rem >> 6, w = rem & 63;
      float keep = 1.0f;
      if (cd.masked && !((h + w) & 1)) keep = 0.0f;  // * (1 - m0): keep odd parity
      f32x4 a = acc[mf][nf];
      outp[obase + rem]           = (a[0] + b0) * keep;
      outp[obase + 4096 + rem]    = (a[1] + b1) * keep;
      outp[obase + 8192 + rem]    = (a[2] + b2) * keep;
      outp[obase + 12288 + rem]   = (a[3] + b3) * keep;
    }
  }
}

extern "C" void kernel_launch(void* const* d_in, const int* in_sizes, int n_in,
                              void* d_out, int out_size, void* d_ws, size_t ws_size,
                              hipStream_t stream) {
  const float* y = (const float*)d_in[0];
  bf16_t* yt = (bf16_t*)d_ws;
  bf16_t* wt = (bf16_t*)((char*)d_ws + (size_t)NPIX * CTOT * 2);  // +20,971,520 B

  k_transpose_y<<<2560, 256, 0, stream>>>(y, yt);

  // Heaviest-first launch order (per-block tap-iters: ch4=100, sp4=72, ch3=50,
  // ch2/ch1=25, sp3=24, sp2/sp1/sp0=12).
  //                        ch4      sp4     ch3     ch2     ch1     sp3     sp2     sp1    sp0
  static const int IC[9]   = {128,    192,    64,     32,     16,     64,     32,     16,    16};
  static const int ICp[9]  = {128,    192,    64,     32,     32,     64,     32,     32,    32};
  static const int OC[9]   = {384,    384,    128,    64,     32,     128,    64,     32,    32};
  static const int OCpA[9] = {384,    384,    128,    64,     64,     128,    64,     64,    64};
  static const int WIDX[9] = {19,     11,     17,     15,     13,     9,      7,      5,     3};
  static const int BIDX[9] = {20,     12,     18,     16,     14,     10,     8,      6,     4};
  static const int CHS[9]  = {0,      128,    0,      0,      0,      64,     32,     16,    0};
  static const int MASKED[9]={0,      1,      0,      0,      0,      1,      1,      1,     1};
  static const unsigned WTOFF[9]  = {2508800, 358400, 2304000, 2252800, 2201600,
                                     153600,  102400, 51200,   0};
  static const unsigned OUTOFF[9] = {28311552, 15728640, 11534336, 5242880, 2097152,
                                     7340032,  3145728,  1048576,  0};
  static const int JOBST[9]  = {0, 384, 768, 896, 960, 1024, 1152, 1216, 1280};

  for (int i = 0; i < 9; ++i) {
    int n = OCpA[i] * ICp[i];
    k_transpose_w<<<(n + 255) / 256, 256, 0, stream>>>(
        (const float*)d_in[WIDX[i]], wt + WTOFF[i], IC[i], ICp[i], OC[i], OCpA[i]);
  }

  MainParams P;
  P.yt = yt; P.wt = wt; P.out = (float*)d_out;
  for (int i = 0; i < 9; ++i) {
    P.cv[i].bias = (const float*)d_in[BIDX[i]];
    P.cv[i].out_off = OUTOFF[i];
    P.cv[i].wt_off = WTOFF[i];
    P.cv[i].IC = IC[i]; P.cv[i].ICp = ICp[i]; P.cv[i].OC = OC[i];
    P.cv[i].chs = CHS[i]; P.cv[i].masked = MASKED[i];
    P.cv[i].job_start = JOBST[i]; P.cv[i].nmb = OCpA[i] >> 6;
  }
  k_conv_main<<<1344, 256, 0, stream>>>(P);
}

// Round 4
// 246.427 us; speedup vs baseline: 1.6051x; 1.3388x over previous
//
#include <hip/hip_runtime.h>

typedef __bf16 bf16_t;
typedef __bf16 bf16x8 __attribute__((ext_vector_type(8)));
typedef float f32x4 __attribute__((ext_vector_type(4)));

#define CTOT 320
#define NPIX 32768  // 8*64*64

#define SIN_PSTRIDE 6544   // 12*68*8 = 6528 + 16 pad (rotates banks by 8 words/icg)
#define SW_PSTRIDE  528    // 64*8    = 512  + 16 pad
#define SW_BUFSTRIDE 2112  // 4 * 528

// ---------- P1: y [b][c][h][w] f32 -> yt [pix][320] bf16 (pixel-major) ----------
__global__ __launch_bounds__(256) void k_transpose_y(const float* __restrict__ y,
                                                     bf16_t* __restrict__ yt) {
  __shared__ bf16_t T[64][72];
  int blk = blockIdx.x;            // (8*64) * 5 blocks
  int c0 = (blk % 5) * 64;
  int bh = blk / 5;                // b*64 + h
  int b = bh >> 6, h = bh & 63;
  int tid = threadIdx.x;
  {
    int c = tid >> 2, w0 = (tid & 3) << 4;
    const float* src = y + (size_t)(b * CTOT + c0 + c) * 4096 + (h << 6) + w0;
#pragma unroll
    for (int j = 0; j < 16; j += 4) {
      float4 v = *(const float4*)(src + j);
      T[c][w0 + j + 0] = (bf16_t)v.x;
      T[c][w0 + j + 1] = (bf16_t)v.y;
      T[c][w0 + j + 2] = (bf16_t)v.z;
      T[c][w0 + j + 3] = (bf16_t)v.w;
    }
  }
  __syncthreads();
  {
    int w = tid >> 2, cq = (tid & 3) << 4;
    union { uint4 v; bf16_t b[8]; } u0, u1;
#pragma unroll
    for (int j = 0; j < 8; ++j) { u0.b[j] = T[cq + j][w]; u1.b[j] = T[cq + 8 + j][w]; }
    bf16_t* dst = yt + (size_t)((bh << 6) | w) * CTOT + c0 + cq;
    *(uint4*)dst = u0.v;
    *(uint4*)(dst + 8) = u1.v;
  }
}

// ---------- P2: w [oc][ic][5][5] f32 -> wt [tap][OCp][ICp] bf16 (zero-padded) ----------
__global__ __launch_bounds__(256) void k_transpose_w(const float* __restrict__ w,
                                                     bf16_t* __restrict__ wt,
                                                     int IC, int ICp, int OC, int OCp) {
  int idx = blockIdx.x * 256 + threadIdx.x;
  if (idx >= OCp * ICp) return;
  int oc = idx / ICp, ic = idx - oc * ICp;
  bool valid = (oc < OC) && (ic < IC);
  const float* src = w + (size_t)(oc * IC + ic) * 25;
#pragma unroll
  for (int t = 0; t < 25; ++t) {
    float v = valid ? src[t] : 0.0f;
    wt[(size_t)(t * OCp + oc) * ICp + ic] = (bf16_t)v;
  }
}

// ---------- main: implicit-GEMM conv, tap-major K, MFMA 16x16x32 bf16 ----------
struct ConvDesc {
  const float* bias;
  unsigned out_off;   // elements into d_out
  unsigned wt_off;    // elements into wt region
  int IC, ICp, OC, chs, masked, job_start, nmb;
};
struct MainParams {
  const bf16_t* yt;
  const bf16_t* wt;
  float* out;
  ConvDesc cv[9];
};

template <bool MASKED>
__device__ __forceinline__ void conv_run(const ConvDesc cd, const MainParams& P,
                                         int local, bf16_t* Sin, bf16_t* Sw) {
  int mb = local >> 6, nb = local & 63;      // 64 n-blocks (512 px each) per m-block
  int b = nb >> 3, r0 = (nb & 7) << 3;       // 8 output rows per n-block
  int tid = threadIdx.x, lane = tid & 63, wn = tid >> 6;
  int OCp = cd.nmb << 6;

  // per-nf fragment base offsets into Sin (elements); tap adds (dy*68+dx)*8
  int bbase[8];
#pragma unroll
  for (int nf = 0; nf < 8; ++nf) {
    int rl = (wn << 1) + (nf >> 2);                 // local output row 0..7
    int col = ((nf & 3) << 4) + (lane & 15);        // local col 0..63
    bbase[nf] = (lane >> 4) * SIN_PSTRIDE + (rl * 68 + col) * 8;
  }
  int abase = (lane >> 4) * SW_PSTRIDE + ((lane & 15) << 3);

  int mfmax = (cd.OC - (mb << 6)) >> 4; if (mfmax > 4) mfmax = 4;

  f32x4 acc[4][8];
#pragma unroll
  for (int i = 0; i < 4; ++i)
#pragma unroll
    for (int j = 0; j < 8; ++j) acc[i][j] = (f32x4){0.f, 0.f, 0.f, 0.f};

  const bf16_t* wtc = P.wt + cd.wt_off;
  int s_oc = tid >> 2, s_icg = tid & 3;
  int swwr = s_icg * SW_PSTRIDE + s_oc * 8;
  constexpr int NT = MASKED ? 12 : 25;

  int nchunks = cd.ICp >> 5;
  for (int cb = 0; cb < nchunks; ++cb) {
    int ic0 = cb << 5;
    // ---- stage input chunk: 12 rows x 68 cols x 32 ic, halo zero-filled ----
    for (int task = tid; task < 3264; task += 256) {
      int pidx = task >> 2, icg = task & 3;
      int rr = pidx / 68, cc = pidx - rr * 68;
      int h = r0 + rr - 2, w = cc - 2;
      int icc = ic0 + (icg << 3);
      uint4 v = {0u, 0u, 0u, 0u};
      if (((unsigned)h < 64u) && ((unsigned)w < 64u) && (icc < cd.IC))
        v = *(const uint4*)(P.yt + (size_t)((((b << 6) + h) << 6) | w) * CTOT + cd.chs + icc);
      *(uint4*)(Sin + icg * SIN_PSTRIDE + pidx * 8) = v;
    }
    // ---- stage weights for tap 0 -> buf 0 ----
    {
      int tap0 = MASKED ? 1 : 0;
      size_t wo = (size_t)(tap0 * OCp + (mb << 6) + s_oc) * cd.ICp + ic0 + (s_icg << 3);
      *(uint4*)(Sw + swwr) = *(const uint4*)(wtc + wo);
    }
    __syncthreads();

#pragma unroll 1
    for (int it = 0; it < NT; ++it) {
      int cur = it & 1;
      uint4 wv;
      if (it + 1 < NT) {  // prefetch next tap's weights (commit after MFMAs)
        int tapn = MASKED ? (2 * it + 3) : (it + 1);
        size_t wo = (size_t)(tapn * OCp + (mb << 6) + s_oc) * cd.ICp + ic0 + (s_icg << 3);
        wv = *(const uint4*)(wtc + wo);
      }
      int tap = MASKED ? (2 * it + 1) : it;
      int dy = tap / 5, dx = tap - dy * 5;
      int toff = (dy * 68 + dx) << 3;

      bf16x8 af[4];
      const bf16_t* swc = Sw + cur * SW_BUFSTRIDE + abase;
#pragma unroll
      for (int mf = 0; mf < 4; ++mf) af[mf] = *(const bf16x8*)(swc + (mf << 7));

      __builtin_amdgcn_s_setprio(1);
#pragma unroll
      for (int nf = 0; nf < 8; ++nf) {
        bf16x8 bfrag = *(const bf16x8*)(Sin + bbase[nf] + toff);
#pragma unroll
        for (int mf = 0; mf < 4; ++mf)
          if (mf < mfmax)
            acc[mf][nf] = __builtin_amdgcn_mfma_f32_16x16x32_bf16(
                af[mf], bfrag, acc[mf][nf], 0, 0, 0);
      }
      __builtin_amdgcn_s_setprio(0);

      if (it + 1 < NT) *(uint4*)(Sw + (cur ^ 1) * SW_BUFSTRIDE + swwr) = wv;
      __syncthreads();
    }
  }

  // ---- epilogue: bias, output mask (1-m0), store f32 ----
  float* outp = P.out + cd.out_off;
  int laneq = lane >> 4;
#pragma unroll
  for (int mf = 0; mf < 4; ++mf) {
    if (mf >= mfmax) break;
    int oc0 = (mb << 6) + (mf << 4) + (laneq << 2);
    float b0 = cd.bias[oc0], b1 = cd.bias[oc0 + 1], b2 = cd.bias[oc0 + 2], b3 = cd.bias[oc0 + 3];
    size_t obase = (size_t)(b * cd.OC + oc0) << 12;
#pragma unroll
    for (int nf = 0; nf < 8; ++nf) {
      int nl = (wn << 7) + (nf << 4) + (lane & 15);
      int rem = (r0 << 6) + nl;
      int h = rem >> 6, w = rem & 63;
      float keep = 1.0f;
      if (MASKED && !((h + w) & 1)) keep = 0.0f;  // * (1 - m0): keep odd parity
      f32x4 a = acc[mf][nf];
      outp[obase + rem]           = (a[0] + b0) * keep;
      outp[obase + 4096 + rem]    = (a[1] + b1) * keep;
      outp[obase + 8192 + rem]    = (a[2] + b2) * keep;
      outp[obase + 12288 + rem]   = (a[3] + b3) * keep;
    }
  }
}

__global__ __launch_bounds__(256, 2) void k_conv_main(MainParams P) {
  __shared__ bf16_t Sin[4 * SIN_PSTRIDE];   // 52352 B
  __shared__ bf16_t Sw[2 * SW_BUFSTRIDE];   //  8448 B

  int bid = blockIdx.x;
  int ci = 0;
#pragma unroll
  for (int i = 1; i < 9; ++i) if (bid >= P.cv[i].job_start) ci = i;
  ConvDesc cd = P.cv[ci];
  int local = bid - cd.job_start;
  if (cd.masked) conv_run<true>(cd, P, local, Sin, Sw);
  else           conv_run<false>(cd, P, local, Sin, Sw);
}

extern "C" void kernel_launch(void* const* d_in, const int* in_sizes, int n_in,
                              void* d_out, int out_size, void* d_ws, size_t ws_size,
                              hipStream_t stream) {
  const float* y = (const float*)d_in[0];
  bf16_t* yt = (bf16_t*)d_ws;
  bf16_t* wt = (bf16_t*)((char*)d_ws + (size_t)NPIX * CTOT * 2);  // +20,971,520 B

  k_transpose_y<<<2560, 256, 0, stream>>>(y, yt);

  // Heaviest-first launch order (per-block tap-iters: ch4=100, sp4=72, ch3=50,
  // ch2/ch1=25, sp3=24, sp2/sp1/sp0=12).
  //                        ch4      sp4     ch3     ch2     ch1     sp3     sp2     sp1    sp0
  static const int IC[9]   = {128,    192,    64,     32,     16,     64,     32,     16,    16};
  static const int ICp[9]  = {128,    192,    64,     32,     32,     64,     32,     32,    32};
  static const int OC[9]   = {384,    384,    128,    64,     32,     128,    64,     32,    32};
  static const int OCpA[9] = {384,    384,    128,    64,     64,     128,    64,     64,    64};
  static const int WIDX[9] = {19,     11,     17,     15,     13,     9,      7,      5,     3};
  static const int BIDX[9] = {20,     12,     18,     16,     14,     10,     8,      6,     4};
  static const int CHS[9]  = {0,      128,    0,      0,      0,      64,     32,     16,    0};
  static const int MASKED[9]={0,      1,      0,      0,      0,      1,      1,      1,     1};
  static const unsigned WTOFF[9]  = {2508800, 358400, 2304000, 2252800, 2201600,
                                     153600,  102400, 51200,   0};
  static const unsigned OUTOFF[9] = {28311552, 15728640, 11534336, 5242880, 2097152,
                                     7340032,  3145728,  1048576,  0};
  static const int JOBST[9]  = {0, 384, 768, 896, 960, 1024, 1152, 1216, 1280};

  for (int i = 0; i < 9; ++i) {
    int n = OCpA[i] * ICp[i];
    k_transpose_w<<<(n + 255) / 256, 256, 0, stream>>>(
        (const float*)d_in[WIDX[i]], wt + WTOFF[i], IC[i], ICp[i], OC[i], OCpA[i]);
  }

  MainParams P;
  P.yt = yt; P.wt = wt; P.out = (float*)d_out;
  for (int i = 0; i < 9; ++i) {
    P.cv[i].bias = (const float*)d_in[BIDX[i]];
    P.cv[i].out_off = OUTOFF[i];
    P.cv[i].wt_off = WTOFF[i];
    P.cv[i].IC = IC[i]; P.cv[i].ICp = ICp[i]; P.cv[i].OC = OC[i];
    P.cv[i].chs = CHS[i]; P.cv[i].masked = MASKED[i];
    P.cv[i].job_start = JOBST[i]; P.cv[i].nmb = OCpA[i] >> 6;
  }
  k_conv_main<<<1344, 256, 0, stream>>>(P);
}

// Round 5
// 196.755 us; speedup vs baseline: 2.0103x; 1.2525x over previous
//
#include <hip/hip_runtime.h>

typedef __bf16 bf16_t;
typedef __bf16 bf16x8 __attribute__((ext_vector_type(8)));
typedef float f32x16 __attribute__((ext_vector_type(16)));

#define CTOT 320
#define NPIX 32768  // 8*64*64

#define SPLANE_U 6544   // (12*68*8)+16 pad
#define SPLANE_M 5776   // (20*36*8)+16 pad
#define SWOFF    13088  // 2*SPLANE_U
// S total = 13088 + 25*1024 = 38688 el = 77376 B -> 2 blocks/CU

// ---------- P1: y [b][c][h][w] f32 -> yt [pix][320] bf16 (dense, pixel-major)
// ----------                       -> ytp [packed even-checkerboard pix][320]
__global__ __launch_bounds__(256) void k_transpose_y(const float* __restrict__ y,
                                                     bf16_t* __restrict__ yt,
                                                     bf16_t* __restrict__ ytp) {
  __shared__ bf16_t T[64][72];
  int blk = blockIdx.x;            // (8*64) * 5 blocks
  int c0 = (blk % 5) * 64;
  int bh = blk / 5;                // b*64 + h
  int b = bh >> 6, h = bh & 63;
  int tid = threadIdx.x;
  {
    int c = tid >> 2, w0 = (tid & 3) << 4;
    const float* src = y + (size_t)(b * CTOT + c0 + c) * 4096 + (h << 6) + w0;
#pragma unroll
    for (int j = 0; j < 16; j += 4) {
      float4 v = *(const float4*)(src + j);
      T[c][w0 + j + 0] = (bf16_t)v.x;
      T[c][w0 + j + 1] = (bf16_t)v.y;
      T[c][w0 + j + 2] = (bf16_t)v.z;
      T[c][w0 + j + 3] = (bf16_t)v.w;
    }
  }
  __syncthreads();
  {
    int w = tid >> 2, cq = (tid & 3) << 4;
    union { uint4 v; bf16_t b[8]; } u0, u1;
#pragma unroll
    for (int j = 0; j < 8; ++j) { u0.b[j] = T[cq + j][w]; u1.b[j] = T[cq + 8 + j][w]; }
    bf16_t* dst = yt + (size_t)((bh << 6) | w) * CTOT + c0 + cq;
    *(uint4*)dst = u0.v;
    *(uint4*)(dst + 8) = u1.v;
  }
  if (tid < 128) {  // packed copy: w = 2j + (h&1)  (even checkerboard)
    int j = tid >> 2, cq = (tid & 3) << 4;
    int w = (j << 1) + (h & 1);
    union { uint4 v; bf16_t b[8]; } u0, u1;
#pragma unroll
    for (int k = 0; k < 8; ++k) { u0.b[k] = T[cq + k][w]; u1.b[k] = T[cq + 8 + k][w]; }
    bf16_t* dst = ytp + (size_t)((bh << 5) + j) * CTOT + c0 + cq;
    *(uint4*)dst = u0.v;
    *(uint4*)(dst + 8) = u1.v;
  }
}

// ---------- P2: w [oc][ic][5][5] f32 -> wt [tap][OCp][IC] bf16 (oc zero-padded)
__global__ __launch_bounds__(256) void k_transpose_w(const float* __restrict__ w,
                                                     bf16_t* __restrict__ wt,
                                                     int IC, int OC, int OCp) {
  int idx = blockIdx.x * 256 + threadIdx.x;
  if (idx >= OCp * IC) return;
  int oc = idx / IC, ic = idx - oc * IC;
  bool valid = (oc < OC);
  const float* src = w + (size_t)(oc * IC + ic) * 25;
#pragma unroll
  for (int t = 0; t < 25; ++t) {
    float v = valid ? src[t] : 0.0f;
    wt[(size_t)(t * OCp + oc) * IC + ic] = (bf16_t)v;
  }
}

// ---------- main: implicit-GEMM conv, 32x32x16 MFMA, K-chunk=16,
// all-taps weights in LDS (no per-tap barriers), masked convs parity-packed.
struct ConvDesc {
  const float* bias;
  int out_off, wt_off;
  int ICp, OC, OCp, chs, masked, job_start;
};
struct MainParams {
  const bf16_t* yt;
  const bf16_t* ytp;
  const bf16_t* wt;
  float* out;
  ConvDesc cv[9];
};

template <bool MASKED>
__device__ __forceinline__ void conv_run(const ConvDesc cd, const MainParams& P,
                                         int local, bf16_t* S) {
  constexpr int NT = MASKED ? 12 : 25;
  constexpr int SPLANE = MASKED ? SPLANE_M : SPLANE_U;
  int mb = MASKED ? (local >> 5) : (local >> 6);
  int nb = local & (MASKED ? 31 : 63);
  int b  = MASKED ? (nb >> 2) : (nb >> 3);
  int hblk = MASKED ? ((nb & 3) << 4) : ((nb & 7) << 3);  // block's first out row
  int tid = threadIdx.x;
  int lane = tid & 63, wn = tid >> 6;
  int l31 = lane & 31, kq = lane >> 5;

  int octmax = (cd.OC - (mb << 6)) >> 5; if (octmax > 2) octmax = 2;

  f32x16 acc00 = {}, acc01 = {}, acc10 = {}, acc11 = {};

  // A-frag read base: Sw[tap][icg(kq)][oc=l31 (+32*ot)][8]
  int aoff = SWOFF + kq * 512 + l31 * 8;
  // B-frag read base
  int boff = MASKED ? (kq * SPLANE_M + ((wn << 1) * 36 + 1 + l31) * 8)
                    : (kq * SPLANE_U + (wn * 68 + l31) * 8);

  const bf16_t* wtc = P.wt + cd.wt_off;
  int nchunks = cd.ICp >> 4;

  for (int cb = 0; cb < nchunks; ++cb) {
    int ic0 = cb << 4;
    if (cb) __syncthreads();
    // ---- stage Sin (16 ic) ----
    if (!MASKED) {
      for (int t = tid; t < 1632; t += 512) {        // 12 rows x 68 cols x 2 icg
        int rr = t / 136, rem = t - rr * 136;
        int cc = rem >> 1, icg = rem & 1;
        int h = hblk + rr - 2, w = cc - 2;
        uint4 v = {0u, 0u, 0u, 0u};
        if (((unsigned)h < 64u) && ((unsigned)w < 64u))
          v = *(const uint4*)(P.yt + (size_t)((((b << 6) + h) << 6) | w) * CTOT + cd.chs + ic0 + (icg << 3));
        *(uint4*)(S + icg * SPLANE_U + (rr * 68 + cc) * 8) = v;
      }
    } else {
      for (int t = tid; t < 1360; t += 512) {        // 20 rows x 34 cols x 2 icg
        int rr = t / 68, rem = t - rr * 68;
        int cc = rem >> 1, icg = rem & 1;
        int h = hblk + rr - 2, j = cc - 1;           // packed col
        uint4 v = {0u, 0u, 0u, 0u};
        if (((unsigned)h < 64u) && ((unsigned)j < 32u))
          v = *(const uint4*)(P.ytp + (size_t)((((b << 6) + h) << 5) + j) * CTOT + cd.chs + ic0 + (icg << 3));
        *(uint4*)(S + icg * SPLANE_M + (rr * 36 + cc) * 8) = v;
      }
    }
    // ---- stage Sw: all NT taps for this chunk ----
    for (int t = tid; t < NT * 128; t += 512) {
      int ti = t >> 7, rem = t & 127;
      int oc = rem >> 1, icg = rem & 1;
      int tap = MASKED ? (2 * ti + 1) : ti;
      int wo = (tap * cd.OCp + (mb << 6) + oc) * cd.ICp + ic0 + (icg << 3);
      *(uint4*)(S + SWOFF + ti * 1024 + icg * 512 + oc * 8) = *(const uint4*)(wtc + wo);
    }
    __syncthreads();

    // ---- barrier-free unrolled tap loop ----
#pragma unroll
    for (int it = 0; it < NT; ++it) {
      int tap = MASKED ? (2 * it + 1) : it;
      int dy = tap / 5, dx = tap - dy * 5;
      bf16x8 af0 = *(const bf16x8*)(S + aoff + it * 1024);
      bf16x8 bf0, bf1;
      if (!MASKED) {
        int toff = (dy * 68 + dx) * 8;
        bf0 = *(const bf16x8*)(S + boff + toff);
        bf1 = *(const bf16x8*)(S + boff + toff + 256);
      } else {
        // packed col shift: joff(rr) = ((rr^1)+dx-2-((rr+dy)&1))/2  (exact, even numerator)
        int j0 = (1 + dx - 2 - (dy & 1)) / 2;
        int j1 = (dx - 2 - ((dy + 1) & 1)) / 2;
        bf0 = *(const bf16x8*)(S + boff + (dy * 36 + j0) * 8);
        bf1 = *(const bf16x8*)(S + boff + ((dy + 1) * 36 + j1) * 8);
      }
      acc00 = __builtin_amdgcn_mfma_f32_32x32x16_bf16(af0, bf0, acc00, 0, 0, 0);
      acc01 = __builtin_amdgcn_mfma_f32_32x32x16_bf16(af0, bf1, acc01, 0, 0, 0);
      if (octmax > 1) {
        bf16x8 af1 = *(const bf16x8*)(S + aoff + it * 1024 + 256);
        acc10 = __builtin_amdgcn_mfma_f32_32x32x16_bf16(af1, bf0, acc10, 0, 0, 0);
        acc11 = __builtin_amdgcn_mfma_f32_32x32x16_bf16(af1, bf1, acc11, 0, 0, 0);
      }
    }
  }

  // ---- epilogue: bias (+ parity packing for masked) ----
  float* outp = P.out + cd.out_off;
#define EPI_U(A, OT, PT)                                                        \
  {                                                                             \
    int h = hblk + wn;                                                          \
    _Pragma("unroll")                                                           \
    for (int r = 0; r < 16; ++r) {                                              \
      int row = (r & 3) + ((r >> 2) << 3) + (kq << 2);                          \
      int oc = (mb << 6) + ((OT) << 5) + row;                                   \
      outp[(size_t)(b * cd.OC + oc) * 4096 + (h << 6) + ((PT) << 5) + l31] =    \
          (A)[r] + cd.bias[oc];                                                 \
    }                                                                           \
  }
#define EPI_M(A, OT, PT)                                                        \
  {                                                                             \
    int h = hblk + (wn << 1) + (PT);                                            \
    _Pragma("unroll")                                                           \
    for (int r = 0; r < 16; ++r) {                                              \
      int row = (r & 3) + ((r >> 2) << 3) + (kq << 2);                          \
      int oc = (mb << 6) + ((OT) << 5) + row;                                   \
      float val = (A)[r] + cd.bias[oc];                                         \
      float2 pr;                                                                \
      if ((PT) == 0) { pr.x = 0.0f; pr.y = val; }                               \
      else           { pr.x = val;  pr.y = 0.0f; }                              \
      *(float2*)(outp + (size_t)(b * cd.OC + oc) * 4096 + (h << 6) + (l31 << 1)) = pr; \
    }                                                                           \
  }
  if (!MASKED) {
    EPI_U(acc00, 0, 0); EPI_U(acc01, 0, 1);
    if (octmax > 1) { EPI_U(acc10, 1, 0); EPI_U(acc11, 1, 1); }
  } else {
    EPI_M(acc00, 0, 0); EPI_M(acc01, 0, 1);
    if (octmax > 1) { EPI_M(acc10, 1, 0); EPI_M(acc11, 1, 1); }
  }
#undef EPI_U
#undef EPI_M
}

__global__ __launch_bounds__(512, 4) void k_conv_main(MainParams P) {
  __shared__ bf16_t S[38688];   // Sin (<=13088) + Sw (25*1024) = 77376 B
  int bid = blockIdx.x;
  int ci = 0;
#pragma unroll
  for (int i = 1; i < 9; ++i) if (bid >= P.cv[i].job_start) ci = i;
  ConvDesc cd = P.cv[ci];
  int local = bid - cd.job_start;
  if (cd.masked) conv_run<true>(cd, P, local, S);
  else           conv_run<false>(cd, P, local, S);
}

extern "C" void kernel_launch(void* const* d_in, const int* in_sizes, int n_in,
                              void* d_out, int out_size, void* d_ws, size_t ws_size,
                              hipStream_t stream) {
  const float* y = (const float*)d_in[0];
  bf16_t* yt  = (bf16_t*)d_ws;                               // 10,485,760 el
  bf16_t* ytp = yt + (size_t)NPIX * CTOT;                    // +5,242,880 el
  bf16_t* wt  = ytp + (size_t)(NPIX / 2) * CTOT;             // +3,660,800 el (~37 MB total)

  k_transpose_y<<<2560, 256, 0, stream>>>(y, yt, ytp);

  // Heaviest-first:      ch4      sp4     ch3     ch2     ch1     sp3     sp2     sp1    sp0
  static const int ICv[9]  = {128,    192,    64,     32,     16,     64,     32,     16,    16};
  static const int OCv[9]  = {384,    384,    128,    64,     32,     128,    64,     32,    32};
  static const int OCp[9]  = {384,    384,    128,    64,     64,     128,    64,     64,    64};
  static const int WIDX[9] = {19,     11,     17,     15,     13,     9,      7,      5,     3};
  static const int BIDX[9] = {20,     12,     18,     16,     14,     10,     8,      6,     4};
  static const int CHS[9]  = {0,      128,    0,      0,      0,      64,     32,     16,    0};
  static const int MSK[9]  = {0,      1,      0,      0,      0,      1,      1,      1,     1};
  static const int WTOFF[9] = {0, 1228800, 3072000, 3276800, 3328000,
                               3353600, 3558400, 3609600, 3635200};
  static const int OUTOFF[9] = {28311552, 15728640, 11534336, 5242880, 2097152,
                                7340032,  3145728,  1048576,  0};
  // blocks: (OCp/64) * (masked ? 32 : 64)
  static const int JOBST[9] = {0, 384, 576, 704, 768, 832, 896, 928, 960};  // total 992

  for (int i = 0; i < 9; ++i) {
    int n = OCp[i] * ICv[i];
    k_transpose_w<<<(n + 255) / 256, 256, 0, stream>>>(
        (const float*)d_in[WIDX[i]], wt + WTOFF[i], ICv[i], OCv[i], OCp[i]);
  }

  MainParams P;
  P.yt = yt; P.ytp = ytp; P.wt = wt; P.out = (float*)d_out;
  for (int i = 0; i < 9; ++i) {
    P.cv[i].bias = (const float*)d_in[BIDX[i]];
    P.cv[i].out_off = OUTOFF[i];
    P.cv[i].wt_off = WTOFF[i];
    P.cv[i].ICp = ICv[i]; P.cv[i].OC = OCv[i]; P.cv[i].OCp = OCp[i];
    P.cv[i].chs = CHS[i]; P.cv[i].masked = MSK[i];
    P.cv[i].job_start = JOBST[i];
  }
  k_conv_main<<<992, 512, 0, stream>>>(P);
}